// Round 15
// baseline (342.164 us; speedup 1.0000x reference)
//
#include <hip/hip_runtime.h>
#include <hip/hip_bf16.h>

#define B_   2
#define S_   2048
#define DIM_ 1024
#define H_   16
#define DH_  64
#define MLP_ 4096

typedef __bf16 bf16x8 __attribute__((ext_vector_type(8)));
typedef float  f32x4  __attribute__((ext_vector_type(4)));

__device__ __forceinline__ ushort f2bf(float f) {
    __bf16 h = (__bf16)f;                    // RNE; compiler packs pairs into v_cvt_pk_bf16_f32
    return __builtin_bit_cast(ushort, h);
}
__device__ __forceinline__ float bf2f(ushort b) {
    union { unsigned u; float f; } x; x.u = ((unsigned)b) << 16;
    return x.f;
}

#define GLOAD_LDS16(gptr, lptr)                                                        \
    __builtin_amdgcn_global_load_lds(                                                  \
        (const __attribute__((address_space(1))) unsigned int*)(const void*)(gptr),    \
        (__attribute__((address_space(3))) unsigned int*)(void*)(lptr), 16, 0, 0)

#define MFMA_BF16(a, b, c) __builtin_amdgcn_mfma_f32_16x16x32_bf16((a), (b), (c), 0, 0, 0)

// counted vmcnt: leaves N VMEM ops in flight (T4). Immediate must be a literal.
template <int N> __device__ __forceinline__ void waitcnt_vm() {
    if constexpr (N == 0)      asm volatile("s_waitcnt vmcnt(0)" ::: "memory");
    else if constexpr (N == 3) asm volatile("s_waitcnt vmcnt(3)" ::: "memory");
    else if constexpr (N == 4) asm volatile("s_waitcnt vmcnt(4)" ::: "memory");
}
__device__ __forceinline__ void pipeline_barrier() {
    __builtin_amdgcn_s_barrier();
    asm volatile("" ::: "memory");   // compiler fence: no LDS-read hoisting above barrier
}

// ---------------- all 4 weight transposes (f32 [K][N] -> bf16 [N][K]) in one launch --
__global__ __launch_bounds__(256) void transpose_all(const float* __restrict__ Wqkv, ushort* __restrict__ Wqkvt,
                                                     const float* __restrict__ Wo,   ushort* __restrict__ Wot,
                                                     const float* __restrict__ W1,   ushort* __restrict__ W1t,
                                                     const float* __restrict__ W2,   ushort* __restrict__ W2t) {
    int id = blockIdx.x;
    const float* in; ushort* outp; int K, N, nx;
    if (id < 3072)      { in = Wqkv; outp = Wqkvt; K = 1024; N = 3072; nx = 96;  }
    else if (id < 4096) { id -= 3072; in = Wo; outp = Wot;  K = 1024; N = 1024; nx = 32;  }
    else if (id < 8192) { id -= 4096; in = W1; outp = W1t;  K = 1024; N = 4096; nx = 128; }
    else                { id -= 8192; in = W2; outp = W2t;  K = 4096; N = 1024; nx = 32;  }
    int n0 = (id % nx) * 32, k0 = (id / nx) * 32;
    __shared__ float t[32][33];
    int tx = threadIdx.x, ty = threadIdx.y;  // block (32,8)
#pragma unroll
    for (int r = 0; r < 32; r += 8)
        t[ty + r][tx] = in[(size_t)(k0 + ty + r) * N + n0 + tx];
    __syncthreads();
#pragma unroll
    for (int r = 0; r < 32; r += 8)
        outp[(size_t)(n0 + ty + r) * K + k0 + tx] = f2bf(t[tx][ty + r]);
}

// ---------------- LayerNorm (f32 in -> bf16 out), one block per row -----------------
__global__ __launch_bounds__(256) void ln_kernel(const float* __restrict__ in,
                                                 const float* __restrict__ g,
                                                 const float* __restrict__ beta,
                                                 ushort* __restrict__ out) {
    int row = blockIdx.x;
    float4 v = reinterpret_cast<const float4*>(in + (size_t)row * DIM_)[threadIdx.x];
    float s = v.x + v.y + v.z + v.w;
    float s2 = v.x * v.x + v.y * v.y + v.z * v.z + v.w * v.w;
#pragma unroll
    for (int m = 1; m < 64; m <<= 1) { s += __shfl_xor(s, m); s2 += __shfl_xor(s2, m); }
    __shared__ float red[8];
    int wid = threadIdx.x >> 6;
    if ((threadIdx.x & 63) == 0) { red[wid] = s; red[4 + wid] = s2; }
    __syncthreads();
    s  = red[0] + red[1] + red[2] + red[3];
    s2 = red[4] + red[5] + red[6] + red[7];
    float mean = s * (1.f / DIM_);
    float var  = s2 * (1.f / DIM_) - mean * mean;
    float inv  = rsqrtf(var + 1e-5f);
    float4 gg = reinterpret_cast<const float4*>(g)[threadIdx.x];
    float4 bb = reinterpret_cast<const float4*>(beta)[threadIdx.x];
    ushort4 o;
    o.x = f2bf((v.x - mean) * inv * gg.x + bb.x);
    o.y = f2bf((v.y - mean) * inv * gg.y + bb.y);
    o.z = f2bf((v.z - mean) * inv * gg.z + bb.z);
    o.w = f2bf((v.w - mean) * inv * gg.w + bb.w);
    reinterpret_cast<ushort4*>(out + (size_t)row * DIM_)[threadIdx.x] = o;
}

// ---------------- GEMM (4 waves): tile (RM*64)x(RN*64), depth-3 pipeline ------------
// Pipeline: stage(0),stage(1) prologue; per iter: vmcnt(L) [t's loads landed, t+1's
// stay in flight ACROSS the barrier], s_barrier, issue stage(t+2), compute buf[t%3].
// Race-check: buf overwrite t+2==t-1 (mod 3) sealed by iter-t barrier; cross-wave
// completion sealed by each wave's vmcnt(L) preceding the shared barrier.
template <int RM, int RN, bool BIAS, bool GELU, bool RES, bool OBF16>
__global__ __launch_bounds__(256) void gemm_bt(const ushort* __restrict__ A,
                                               const ushort* __restrict__ Bt,
                                               void* __restrict__ Cout,
                                               const float* __restrict__ bias,
                                               const float* __restrict__ resid,
                                               int M, int N, int K) {
    constexpr int BM = RM * 64, BN = RN * 64, L = RM + RN;
    __shared__ __align__(16) ushort As[3][BM * 32];
    __shared__ __align__(16) ushort Bs[3][BN * 32];
    int tid = threadIdx.x;
    int wid = tid >> 6, lane = tid & 63;
    int lr = lane & 15, lg = lane >> 4;

    int nbx = gridDim.x;
    int nwg = nbx * gridDim.y;
    int bid = blockIdx.y * nbx + blockIdx.x;
    int swz = (bid & 7) * (nwg >> 3) + (bid >> 3);  // bijective: nwg % 8 == 0
    int row0 = (swz / nbx) * BM, col0 = (swz % nbx) * BN;

    int wm = (wid >> 1) * (RM * 32), wn = (wid & 1) * (RN * 32);
    int srow = tid >> 2, scol = (tid & 3) * 8;

    f32x4 acc[RM * 2][RN * 2] = {};

    const ushort* gA = A + (size_t)(row0 + srow) * K + scol;
    const ushort* gB = Bt + (size_t)(col0 + srow) * K + scol;

    auto stage = [&](int buf, int kt) {
#pragma unroll
        for (int r = 0; r < RM; r++)
            GLOAD_LDS16(gA + (size_t)r * 64 * K + kt, As[buf] + r * 2048 + wid * 512);
#pragma unroll
        for (int r = 0; r < RN; r++)
            GLOAD_LDS16(gB + (size_t)r * 64 * K + kt, Bs[buf] + r * 2048 + wid * 512);
    };

    int nk = K >> 5;          // nk >= 32 for all our shapes
    stage(0, 0);
    stage(1, 32);

    for (int t = 0; t < nk; t++) {
        int cur = t % 3;
        if (t + 1 < nk) waitcnt_vm<L>();
        else            waitcnt_vm<0>();
        pipeline_barrier();
        if (t + 2 < nk) stage((t + 2) % 3, (t + 2) << 5);
        bf16x8 af[RM * 2], bfr[RN * 2];
#pragma unroll
        for (int m = 0; m < RM * 2; m++)
            af[m] = *reinterpret_cast<const bf16x8*>(As[cur] + (wm + m * 16 + lr) * 32 + lg * 8);
#pragma unroll
        for (int n = 0; n < RN * 2; n++)
            bfr[n] = *reinterpret_cast<const bf16x8*>(Bs[cur] + (wn + n * 16 + lr) * 32 + lg * 8);
#pragma unroll
        for (int m = 0; m < RM * 2; m++)
#pragma unroll
            for (int n = 0; n < RN * 2; n++)
                acc[m][n] = MFMA_BF16(af[m], bfr[n], acc[m][n]);
    }

#pragma unroll
    for (int m = 0; m < RM * 2; m++) {
#pragma unroll
        for (int n = 0; n < RN * 2; n++) {
            int col = col0 + wn + n * 16 + lr;
#pragma unroll
            for (int i = 0; i < 4; i++) {
                int row = row0 + wm + m * 16 + lg * 4 + i;
                float v = acc[m][n][i];
                if (BIAS) v += bias[col];
                if (GELU) v = 0.5f * v * (1.f + erff(v * 0.70710678118f));
                if (RES)  v += resid[(size_t)row * N + col];
                if (OBF16) ((ushort*)Cout)[(size_t)row * N + col] = f2bf(v);
                else       ((float*)Cout)[(size_t)row * N + col] = v;
            }
        }
    }
}

// ---------------- GEMM (8 waves, 512 thr): 128x256 tile, depth-3 pipeline -----------
template <bool BIAS, bool GELU, bool RES, bool OBF16>
__global__ __launch_bounds__(512) void gemm_bt512(const ushort* __restrict__ A,
                                                  const ushort* __restrict__ Bt,
                                                  void* __restrict__ Cout,
                                                  const float* __restrict__ bias,
                                                  const float* __restrict__ resid,
                                                  int M, int N, int K) {
    __shared__ __align__(16) ushort As[3][128 * 32];
    __shared__ __align__(16) ushort Bs[3][256 * 32];
    int tid = threadIdx.x;
    int wid = tid >> 6, lane = tid & 63;
    int lr = lane & 15, lg = lane >> 4;

    int nbx = gridDim.x;
    int nwg = nbx * gridDim.y;
    int bid = blockIdx.y * nbx + blockIdx.x;
    int swz = (bid & 7) * (nwg >> 3) + (bid >> 3);
    int row0 = (swz / nbx) * 128, col0 = (swz % nbx) * 256;

    int wm = (wid >> 2) * 64, wn = (wid & 3) * 64;
    int srow = tid >> 2, scol = (tid & 3) * 8;   // 512 threads: 128 rows x 4 chunks

    f32x4 acc[4][4] = {};

    const ushort* gA = A + (size_t)(row0 + srow) * K + scol;
    const ushort* gB = Bt + (size_t)(col0 + srow) * K + scol;

    auto stage = [&](int buf, int kt) {
        GLOAD_LDS16(gA + kt, As[buf] + wid * 512);                          // A rows 0-127
        GLOAD_LDS16(gB + kt, Bs[buf] + wid * 512);                          // B rows 0-127
        GLOAD_LDS16(gB + (size_t)128 * K + kt, Bs[buf] + 4096 + wid * 512); // B rows 128-255
    };

    int nk = K >> 5;
    stage(0, 0);
    stage(1, 32);

    for (int t = 0; t < nk; t++) {
        int cur = t % 3;
        if (t + 1 < nk) waitcnt_vm<3>();
        else            waitcnt_vm<0>();
        pipeline_barrier();
        if (t + 2 < nk) stage((t + 2) % 3, (t + 2) << 5);
        bf16x8 af[4], bfr[4];
#pragma unroll
        for (int m = 0; m < 4; m++)
            af[m] = *reinterpret_cast<const bf16x8*>(As[cur] + (wm + m * 16 + lr) * 32 + lg * 8);
#pragma unroll
        for (int n = 0; n < 4; n++)
            bfr[n] = *reinterpret_cast<const bf16x8*>(Bs[cur] + (wn + n * 16 + lr) * 32 + lg * 8);
#pragma unroll
        for (int m = 0; m < 4; m++)
#pragma unroll
            for (int n = 0; n < 4; n++)
                acc[m][n] = MFMA_BF16(af[m], bfr[n], acc[m][n]);
    }

#pragma unroll
    for (int m = 0; m < 4; m++) {
#pragma unroll
        for (int n = 0; n < 4; n++) {
            int col = col0 + wn + n * 16 + lr;
#pragma unroll
            for (int i = 0; i < 4; i++) {
                int row = row0 + wm + m * 16 + lg * 4 + i;
                float v = acc[m][n][i];
                if (BIAS) v += bias[col];
                if (GELU) v = 0.5f * v * (1.f + erff(v * 0.70710678118f));
                if (RES)  v += resid[(size_t)row * N + col];
                if (OBF16) ((ushort*)Cout)[(size_t)row * N + col] = f2bf(v);
                else       ((float*)Cout)[(size_t)row * N + col] = v;
            }
        }
    }
}

// ---------------- QKV GEMM (8 waves, 128x256) fused RoPE + V^T, depth-3 pipeline ----
__global__ __launch_bounds__(512) void gemm_qkv512(const ushort* __restrict__ A,
                                                   const ushort* __restrict__ Bt,
                                                   const float2* __restrict__ tab,
                                                   ushort* __restrict__ Qr,
                                                   ushort* __restrict__ Kr,
                                                   ushort* __restrict__ VT) {
    const int K = DIM_;
    __shared__ __align__(16) ushort As[3][128 * 32];
    __shared__ __align__(16) ushort Bs[3][256 * 32];
    int tid = threadIdx.x;
    int wid = tid >> 6, lane = tid & 63;
    int lr = lane & 15, lg = lane >> 4;

    int nbx = gridDim.x;
    int nwg = nbx * gridDim.y;
    int bid = blockIdx.y * nbx + blockIdx.x;
    int swz = (bid & 7) * (nwg >> 3) + (bid >> 3);
    int row0 = (swz / nbx) * 128, col0 = (swz % nbx) * 256;

    int wm = (wid >> 2) * 64, wn = (wid & 3) * 64;
    int srow = tid >> 2, scol = (tid & 3) * 8;

    f32x4 acc[4][4] = {};

    const ushort* gA = A + (size_t)(row0 + srow) * K + scol;
    const ushort* gB = Bt + (size_t)(col0 + srow) * K + scol;

    auto stage = [&](int buf, int kt) {
        GLOAD_LDS16(gA + kt, As[buf] + wid * 512);
        GLOAD_LDS16(gB + kt, Bs[buf] + wid * 512);
        GLOAD_LDS16(gB + (size_t)128 * K + kt, Bs[buf] + 4096 + wid * 512);
    };

    int nk = K >> 5;
    stage(0, 0);
    stage(1, 32);

    for (int t = 0; t < nk; t++) {
        int cur = t % 3;
        if (t + 1 < nk) waitcnt_vm<3>();
        else            waitcnt_vm<0>();
        pipeline_barrier();
        if (t + 2 < nk) stage((t + 2) % 3, (t + 2) << 5);
        bf16x8 af[4], bfr[4];
#pragma unroll
        for (int m = 0; m < 4; m++)
            af[m] = *reinterpret_cast<const bf16x8*>(As[cur] + (wm + m * 16 + lr) * 32 + lg * 8);
#pragma unroll
        for (int n = 0; n < 4; n++)
            bfr[n] = *reinterpret_cast<const bf16x8*>(Bs[cur] + (wn + n * 16 + lr) * 32 + lg * 8);
#pragma unroll
        for (int m = 0; m < 4; m++)
#pragma unroll
            for (int n = 0; n < 4; n++)
                acc[m][n] = MFMA_BF16(af[m], bfr[n], acc[m][n]);
    }

#pragma unroll
    for (int n = 0; n < 4; n++) {
        int colb = col0 + wn + n * 16;     // uniform per fragment; 16-aligned in a 64-block
        int h    = colb / 192;
        int off  = colb % 192;
        int typ  = off >> 6;               // 0=q, 1=k, 2=v
        int d    = (off & 63) + lr;        // per-lane head dim
#pragma unroll
        for (int m = 0; m < 4; m++) {
            if (typ < 2) {
                ushort* qk = (typ == 0) ? Qr : Kr;
#pragma unroll
                for (int i = 0; i < 4; i++) {
                    int row = row0 + wm + m * 16 + lg * 4 + i;
                    int b = row >> 11, s = row & (S_ - 1);
                    float v  = acc[m][n][i];
                    float pv = __shfl_xor(v, 1);   // partner lane holds x_{d^1}
                    float2 cs = tab[(s << 5) + (d >> 1)];
                    float r = v * cs.x + ((d & 1) ? pv : -pv) * cs.y;
                    qk[((size_t)(b * H_ + h) * S_ + s) * DH_ + d] = f2bf(r);
                }
            } else {
                int row = row0 + wm + m * 16 + lg * 4;
                int b = row >> 11, s = row & (S_ - 1);
                ushort4 o4;
                o4.x = f2bf(acc[m][n][0]);
                o4.y = f2bf(acc[m][n][1]);
                o4.z = f2bf(acc[m][n][2]);
                o4.w = f2bf(acc[m][n][3]);
                *reinterpret_cast<ushort4*>(
                    VT + ((size_t)(b * H_ + h) * DH_ + d) * S_ + s) = o4;
            }
        }
    }
}

// ---------------- RoPE table ---------------------------------------------------------
__global__ __launch_bounds__(256) void rope_table(float2* __restrict__ tab) {
    int i = blockIdx.x * 256 + threadIdx.x;  // S_*32 threads
    int s = i >> 5, p = i & 31;
    float invf = __expf(-((float)(2 * p) / 64.f) * logf(10000.f));
    float a = (float)s * invf;
    tab[i] = make_float2(cosf(a), sinf(a));
}

// ---------------- Flash attention (exact R9/R6 structure, measured 128 us) ----------
__global__ __launch_bounds__(256) void attn_kernel(const ushort* __restrict__ Q,
                                                   const ushort* __restrict__ Kr,
                                                   const ushort* __restrict__ VT,
                                                   const float* __restrict__ bias,
                                                   const int* __restrict__ pad,
                                                   ushort* __restrict__ Out) {
    int bx = blockIdx.x;
    int qt = bx & 31, h = (bx >> 5) & 15, b = bx >> 9;
    __shared__ __align__(16) ushort Ks[64 * 72];
    __shared__ __align__(16) ushort Vs[64 * 72];
    __shared__ __align__(16) ushort Ps[64 * 72];  // 4 waves x 16 rows
    int tid = threadIdx.x, wid = tid >> 6, lane = tid & 63;
    int lr = lane & 15, lg = lane >> 4;
    int q0 = qt * 64;
    const ushort* Qb = Q + ((size_t)(b * H_ + h) * S_) * DH_;
    const ushort* Kb = Kr + ((size_t)(b * H_ + h) * S_) * DH_;
    const ushort* Vb = VT + ((size_t)(b * H_ + h) * DH_) * S_;
    const float*  bb = bias + (size_t)b * S_ * S_;
    const int*    pb = pad + b * S_;

    bf16x8 qf[2];
#pragma unroll
    for (int ks = 0; ks < 2; ks++)
        qf[ks] = *reinterpret_cast<const bf16x8*>(
            Qb + (size_t)(q0 + wid * 16 + lr) * DH_ + ks * 32 + lg * 8);

    float mrow[4], lrow[4];
#pragma unroll
    for (int i = 0; i < 4; i++) { mrow[i] = -3e38f; lrow[i] = 0.f; }
    f32x4 o[4] = {};

    int sr = tid >> 3, sc = (tid & 7) * 8;
    const float scale = 0.125f;  // dh^-0.5

    for (int kv0 = 0; kv0 < S_; kv0 += 64) {
        __syncthreads();
#pragma unroll
        for (int cc = 0; cc < 2; cc++) {
            int r = cc * 32 + sr;
            *reinterpret_cast<bf16x8*>(Ks + r * 72 + sc) =
                *reinterpret_cast<const bf16x8*>(Kb + (size_t)(kv0 + r) * DH_ + sc);
            *reinterpret_cast<bf16x8*>(Vs + r * 72 + sc) =
                *reinterpret_cast<const bf16x8*>(Vb + (size_t)r * S_ + kv0 + sc);
        }
        __syncthreads();

        // S = Q K^T
        f32x4 sa[4] = {};
#pragma unroll
        for (int n = 0; n < 4; n++) {
            bf16x8 k0 = *reinterpret_cast<const bf16x8*>(Ks + (n * 16 + lr) * 72 + lg * 8);
            bf16x8 k1 = *reinterpret_cast<const bf16x8*>(Ks + (n * 16 + lr) * 72 + 32 + lg * 8);
            sa[n] = MFMA_BF16(qf[0], k0, sa[n]);
            sa[n] = MFMA_BF16(qf[1], k1, sa[n]);
        }

        int pm[4];
#pragma unroll
        for (int n = 0; n < 4; n++) pm[n] = pb[kv0 + n * 16 + lr];

        // online softmax, rows = q0 + wid*16 + lg*4 + i
#pragma unroll
        for (int i = 0; i < 4; i++) {
            const float* brow = bb + (size_t)(q0 + wid * 16 + lg * 4 + i) * S_ + kv0;
            float sv[4];
            float rmax = -3e38f;
#pragma unroll
            for (int n = 0; n < 4; n++) {
                float s = sa[n][i] * scale + brow[n * 16 + lr];
                if (pm[n]) s = -1e30f;
                sv[n] = s;
                rmax = fmaxf(rmax, s);
            }
#pragma unroll
            for (int msk = 1; msk < 16; msk <<= 1) rmax = fmaxf(rmax, __shfl_xor(rmax, msk));
            float mnew = fmaxf(mrow[i], rmax);
            float resc = __expf(mrow[i] - mnew);
            mrow[i] = mnew;
            float ls = 0.f;
            int prow = (i << 2) | lg;  // bit-swapped physical row (bank-spread)
#pragma unroll
            for (int n = 0; n < 4; n++) {
                float p = __expf(sv[n] - mnew);
                ls += p;
                Ps[(wid * 16 + prow) * 72 + n * 16 + lr] = f2bf(p);
            }
            lrow[i] = lrow[i] * resc + ls;  // per-lane partial sum (reduced at end)
#pragma unroll
            for (int fn = 0; fn < 4; fn++) o[fn][i] *= resc;
        }

        // P A-frags (wave-private Ps: no barrier needed)
        int plr = ((lr & 3) << 2) | (lr >> 2);  // same bit-swap
        bf16x8 pf0 = *reinterpret_cast<const bf16x8*>(Ps + (wid * 16 + plr) * 72 + lg * 8);
        bf16x8 pf1 = *reinterpret_cast<const bf16x8*>(Ps + (wid * 16 + plr) * 72 + 32 + lg * 8);

        // O += P @ V   (V B-frags from V^T rows)
#pragma unroll
        for (int fn = 0; fn < 4; fn++) {
            bf16x8 v0 = *reinterpret_cast<const bf16x8*>(Vs + (fn * 16 + lr) * 72 + lg * 8);
            bf16x8 v1 = *reinterpret_cast<const bf16x8*>(Vs + (fn * 16 + lr) * 72 + 32 + lg * 8);
            o[fn] = MFMA_BF16(pf0, v0, o[fn]);
            o[fn] = MFMA_BF16(pf1, v1, o[fn]);
        }
    }

    // reduce per-lane partial sums across the 16-lane row group
#pragma unroll
    for (int i = 0; i < 4; i++)
#pragma unroll
        for (int msk = 1; msk < 16; msk <<= 1) lrow[i] += __shfl_xor(lrow[i], msk);

#pragma unroll
    for (int fn = 0; fn < 4; fn++)
#pragma unroll
        for (int i = 0; i < 4; i++) {
            int qrow = q0 + wid * 16 + lg * 4 + i;
            Out[(size_t)(b * S_ + qrow) * DIM_ + h * DH_ + fn * 16 + lr] =
                f2bf(o[fn][i] / lrow[i]);
        }
}

// ------------------------------------ launch ----------------------------------------
extern "C" void kernel_launch(void* const* d_in, const int* in_sizes, int n_in,
                              void* d_out, int out_size, void* d_ws, size_t ws_size,
                              hipStream_t stream) {
    const float* x    = (const float*)d_in[0];
    const float* bias = (const float*)d_in[1];
    const float* ln1g = (const float*)d_in[2];
    const float* ln1b = (const float*)d_in[3];
    const float* Wqkv = (const float*)d_in[4];
    const float* Wo   = (const float*)d_in[5];
    const float* ln2g = (const float*)d_in[6];
    const float* ln2b = (const float*)d_in[7];
    const float* W1   = (const float*)d_in[8];
    const float* b1   = (const float*)d_in[9];
    const float* W2   = (const float*)d_in[10];
    const float* b2   = (const float*)d_in[11];
    const int*   pad  = (const int*)d_in[12];
    float* out = (float*)d_out;

    char* ws = (char*)d_ws;
    size_t off = 0;
    auto alloc = [&](size_t bytes) {
        char* p = ws + off;
        off += (bytes + 255) & ~(size_t)255;
        return (void*)p;
    };
    ushort* x1    = (ushort*)alloc((size_t)4096 * 1024 * 2);
    ushort* Wqkvt = (ushort*)alloc((size_t)3072 * 1024 * 2);
    float2* tab   = (float2*)alloc((size_t)S_ * 32 * 8);
    ushort* Qr    = (ushort*)alloc((size_t)B_ * H_ * S_ * DH_ * 2);
    ushort* Kr2   = (ushort*)alloc((size_t)B_ * H_ * S_ * DH_ * 2);
    ushort* attnO = (ushort*)alloc((size_t)4096 * 1024 * 2);
    ushort* Wot   = (ushort*)alloc((size_t)1024 * 1024 * 2);
    float*  xmid  = (float*)alloc((size_t)4096 * 1024 * 4);
    ushort* x2    = (ushort*)alloc((size_t)4096 * 1024 * 2);
    ushort* W1t   = (ushort*)alloc((size_t)4096 * 1024 * 2);
    ushort* h1    = (ushort*)alloc((size_t)4096 * 4096 * 2);
    ushort* W2t   = (ushort*)alloc((size_t)1024 * 4096 * 2);
    // VT aliases h1: VT is consumed by attn_kernel, h1 first written after attn.
    ushort* VT    = h1;  // [B,H,DH,S] = 8 MB

    dim3 tb(32, 8);
    transpose_all<<<12288, tb, 0, stream>>>(Wqkv, Wqkvt, Wo, Wot, W1, W1t, W2, W2t);

    rope_table<<<(S_ * 32) / 256, 256, 0, stream>>>(tab);

    ln_kernel<<<4096, 256, 0, stream>>>(x, ln1g, ln1b, x1);

    // QKV GEMM (128x256, 8 waves, depth-3 pipeline) with fused RoPE + V^T epilogue
    gemm_qkv512<<<dim3(12, 32), 512, 0, stream>>>(x1, Wqkvt, tab, Qr, Kr2, VT);

    attn_kernel<<<B_ * H_ * (S_ / 64), 256, 0, stream>>>(Qr, Kr2, VT, bias, pad, attnO);

    // O-proj: 64x128 tile -> 512 blocks (2/CU)
    gemm_bt<1, 2, false, false, true, false><<<dim3(8, 64), 256, 0, stream>>>(
        attnO, Wot, xmid, nullptr, x, 4096, 1024, 1024);

    ln_kernel<<<4096, 256, 0, stream>>>(xmid, ln2g, ln2b, x2);

    // MLP1: 128x256 tile, 8 waves, depth-3 pipeline -> 512 blocks
    gemm_bt512<true, true, false, true><<<dim3(16, 32), 512, 0, stream>>>(
        x2, W1t, h1, b1, nullptr, 4096, 4096, 1024);

    // MLP2: 64x128 tile -> 512 blocks (2/CU)
    gemm_bt<1, 2, true, false, true, false><<<dim3(8, 64), 256, 0, stream>>>(
        h1, W2t, out, b2, xmid, 4096, 1024, 4096);
}

// Round 16
// 306.619 us; speedup vs baseline: 1.1159x; 1.1159x over previous
//
#include <hip/hip_runtime.h>
#include <hip/hip_bf16.h>

#define B_   2
#define S_   2048
#define DIM_ 1024
#define H_   16
#define DH_  64
#define MLP_ 4096

typedef __bf16 bf16x8 __attribute__((ext_vector_type(8)));
typedef float  f32x4  __attribute__((ext_vector_type(4)));

__device__ __forceinline__ ushort f2bf(float f) {
    __bf16 h = (__bf16)f;                    // RNE; compiler packs pairs into v_cvt_pk_bf16_f32
    return __builtin_bit_cast(ushort, h);
}
__device__ __forceinline__ float bf2f(ushort b) {
    union { unsigned u; float f; } x; x.u = ((unsigned)b) << 16;
    return x.f;
}

#define GLOAD_LDS16(gptr, lptr)                                                        \
    __builtin_amdgcn_global_load_lds(                                                  \
        (const __attribute__((address_space(1))) unsigned int*)(const void*)(gptr),    \
        (__attribute__((address_space(3))) unsigned int*)(void*)(lptr), 16, 0, 0)

#define MFMA_BF16(a, b, c) __builtin_amdgcn_mfma_f32_16x16x32_bf16((a), (b), (c), 0, 0, 0)

// ---------------- all 4 weight transposes (f32 [K][N] -> bf16 [N][K]) in one launch --
__global__ __launch_bounds__(256) void transpose_all(const float* __restrict__ Wqkv, ushort* __restrict__ Wqkvt,
                                                     const float* __restrict__ Wo,   ushort* __restrict__ Wot,
                                                     const float* __restrict__ W1,   ushort* __restrict__ W1t,
                                                     const float* __restrict__ W2,   ushort* __restrict__ W2t) {
    int id = blockIdx.x;
    const float* in; ushort* outp; int K, N, nx;
    if (id < 3072)      { in = Wqkv; outp = Wqkvt; K = 1024; N = 3072; nx = 96;  }
    else if (id < 4096) { id -= 3072; in = Wo; outp = Wot;  K = 1024; N = 1024; nx = 32;  }
    else if (id < 8192) { id -= 4096; in = W1; outp = W1t;  K = 1024; N = 4096; nx = 128; }
    else                { id -= 8192; in = W2; outp = W2t;  K = 4096; N = 1024; nx = 32;  }
    int n0 = (id % nx) * 32, k0 = (id / nx) * 32;
    __shared__ float t[32][33];
    int tx = threadIdx.x, ty = threadIdx.y;  // block (32,8)
#pragma unroll
    for (int r = 0; r < 32; r += 8)
        t[ty + r][tx] = in[(size_t)(k0 + ty + r) * N + n0 + tx];
    __syncthreads();
#pragma unroll
    for (int r = 0; r < 32; r += 8)
        outp[(size_t)(n0 + ty + r) * K + k0 + tx] = f2bf(t[tx][ty + r]);
}

// ---------------- LayerNorm (f32 in -> bf16 out), one block per row -----------------
__global__ __launch_bounds__(256) void ln_kernel(const float* __restrict__ in,
                                                 const float* __restrict__ g,
                                                 const float* __restrict__ beta,
                                                 ushort* __restrict__ out) {
    int row = blockIdx.x;
    float4 v = reinterpret_cast<const float4*>(in + (size_t)row * DIM_)[threadIdx.x];
    float s = v.x + v.y + v.z + v.w;
    float s2 = v.x * v.x + v.y * v.y + v.z * v.z + v.w * v.w;
#pragma unroll
    for (int m = 1; m < 64; m <<= 1) { s += __shfl_xor(s, m); s2 += __shfl_xor(s2, m); }
    __shared__ float red[8];
    int wid = threadIdx.x >> 6;
    if ((threadIdx.x & 63) == 0) { red[wid] = s; red[4 + wid] = s2; }
    __syncthreads();
    s  = red[0] + red[1] + red[2] + red[3];
    s2 = red[4] + red[5] + red[6] + red[7];
    float mean = s * (1.f / DIM_);
    float var  = s2 * (1.f / DIM_) - mean * mean;
    float inv  = rsqrtf(var + 1e-5f);
    float4 gg = reinterpret_cast<const float4*>(g)[threadIdx.x];
    float4 bb = reinterpret_cast<const float4*>(beta)[threadIdx.x];
    ushort4 o;
    o.x = f2bf((v.x - mean) * inv * gg.x + bb.x);
    o.y = f2bf((v.y - mean) * inv * gg.y + bb.y);
    o.z = f2bf((v.z - mean) * inv * gg.z + bb.z);
    o.w = f2bf((v.w - mean) * inv * gg.w + bb.w);
    reinterpret_cast<ushort4*>(out + (size_t)row * DIM_)[threadIdx.x] = o;
}

// ---------------- GEMM (4 waves): tile (RM*64)x(RN*64), 2 K-steps per barrier -------
// R14 2-phase semantics (plain __syncthreads, no hand vmcnt — R15 showed counted
// vmcnt on this structure regresses). Pair-unroll: 4 buffers (2 pairs x 2 subs);
// per iteration prefetch the NEXT pair (2 K-steps), compute the current pair,
// one barrier. Halves barrier count; keeps BK=32 bank geometry.
template <int RM, int RN, bool BIAS, bool GELU, bool RES, bool OBF16>
__global__ __launch_bounds__(256) void gemm_bt(const ushort* __restrict__ A,
                                               const ushort* __restrict__ Bt,
                                               void* __restrict__ Cout,
                                               const float* __restrict__ bias,
                                               const float* __restrict__ resid,
                                               int M, int N, int K) {
    constexpr int BM = RM * 64, BN = RN * 64;
    __shared__ __align__(16) ushort As[2][2][BM * 32];
    __shared__ __align__(16) ushort Bs[2][2][BN * 32];
    int tid = threadIdx.x;
    int wid = tid >> 6, lane = tid & 63;
    int lr = lane & 15, lg = lane >> 4;

    int nbx = gridDim.x;
    int nwg = nbx * gridDim.y;
    int bid = blockIdx.y * nbx + blockIdx.x;
    int swz = (bid & 7) * (nwg >> 3) + (bid >> 3);  // bijective: nwg % 8 == 0
    int row0 = (swz / nbx) * BM, col0 = (swz % nbx) * BN;

    int wm = (wid >> 1) * (RM * 32), wn = (wid & 1) * (RN * 32);
    int srow = tid >> 2, scol = (tid & 3) * 8;

    f32x4 acc[RM * 2][RN * 2] = {};

    const ushort* gA = A + (size_t)(row0 + srow) * K + scol;
    const ushort* gB = Bt + (size_t)(col0 + srow) * K + scol;

    auto stage = [&](int buf, int sub, int kt) {
#pragma unroll
        for (int r = 0; r < RM; r++)
            GLOAD_LDS16(gA + (size_t)r * 64 * K + kt, As[buf][sub] + r * 2048 + wid * 512);
#pragma unroll
        for (int r = 0; r < RN; r++)
            GLOAD_LDS16(gB + (size_t)r * 64 * K + kt, Bs[buf][sub] + r * 2048 + wid * 512);
    };

    int nk = K >> 5;                 // even for all our shapes (32 or 128)
    stage(0, 0, 0);
    stage(0, 1, 32);
    __syncthreads();

    for (int t = 0; t < nk; t += 2) {
        int cur = (t >> 1) & 1;
        if (t + 2 < nk) {            // prefetch next pair; flies under 2 K-steps of MFMA
            stage(cur ^ 1, 0, (t + 2) << 5);
            stage(cur ^ 1, 1, (t + 3) << 5);
        }
#pragma unroll
        for (int sub = 0; sub < 2; sub++) {
            bf16x8 af[RM * 2], bfr[RN * 2];
#pragma unroll
            for (int m = 0; m < RM * 2; m++)
                af[m] = *reinterpret_cast<const bf16x8*>(As[cur][sub] + (wm + m * 16 + lr) * 32 + lg * 8);
#pragma unroll
            for (int n = 0; n < RN * 2; n++)
                bfr[n] = *reinterpret_cast<const bf16x8*>(Bs[cur][sub] + (wn + n * 16 + lr) * 32 + lg * 8);
#pragma unroll
            for (int m = 0; m < RM * 2; m++)
#pragma unroll
                for (int n = 0; n < RN * 2; n++)
                    acc[m][n] = MFMA_BF16(af[m], bfr[n], acc[m][n]);
        }
        __syncthreads();             // drains prefetch + all reads of cur done
    }

#pragma unroll
    for (int m = 0; m < RM * 2; m++) {
#pragma unroll
        for (int n = 0; n < RN * 2; n++) {
            int col = col0 + wn + n * 16 + lr;
#pragma unroll
            for (int i = 0; i < 4; i++) {
                int row = row0 + wm + m * 16 + lg * 4 + i;
                float v = acc[m][n][i];
                if (BIAS) v += bias[col];
                if (GELU) v = 0.5f * v * (1.f + erff(v * 0.70710678118f));
                if (RES)  v += resid[(size_t)row * N + col];
                if (OBF16) ((ushort*)Cout)[(size_t)row * N + col] = f2bf(v);
                else       ((float*)Cout)[(size_t)row * N + col] = v;
            }
        }
    }
}

// ---------------- GEMM (8 waves, 512 thr): 128x256 tile, BK=32 (R14 exact) ----------
template <bool BIAS, bool GELU, bool RES, bool OBF16>
__global__ __launch_bounds__(512) void gemm_bt512(const ushort* __restrict__ A,
                                                  const ushort* __restrict__ Bt,
                                                  void* __restrict__ Cout,
                                                  const float* __restrict__ bias,
                                                  const float* __restrict__ resid,
                                                  int M, int N, int K) {
    __shared__ __align__(16) ushort As[2][128 * 32];
    __shared__ __align__(16) ushort Bs[2][256 * 32];
    int tid = threadIdx.x;
    int wid = tid >> 6, lane = tid & 63;
    int lr = lane & 15, lg = lane >> 4;

    int nbx = gridDim.x;
    int nwg = nbx * gridDim.y;
    int bid = blockIdx.y * nbx + blockIdx.x;
    int swz = (bid & 7) * (nwg >> 3) + (bid >> 3);
    int row0 = (swz / nbx) * 128, col0 = (swz % nbx) * 256;

    int wm = (wid >> 2) * 64, wn = (wid & 3) * 64;
    int srow = tid >> 2, scol = (tid & 3) * 8;   // 512 threads: 128 rows x 4 chunks

    f32x4 acc[4][4] = {};

    const ushort* gA = A + (size_t)(row0 + srow) * K + scol;
    const ushort* gB = Bt + (size_t)(col0 + srow) * K + scol;

    auto stage = [&](int buf, int kt) {
        GLOAD_LDS16(gA + kt, As[buf] + wid * 512);                          // A rows 0-127
        GLOAD_LDS16(gB + kt, Bs[buf] + wid * 512);                          // B rows 0-127
        GLOAD_LDS16(gB + (size_t)128 * K + kt, Bs[buf] + 4096 + wid * 512); // B rows 128-255
    };

    int nk = K >> 5;
    stage(0, 0);
    __syncthreads();

    for (int t = 0; t < nk; t++) {
        int cur = t & 1;
        if (t + 1 < nk) stage(cur ^ 1, (t + 1) << 5);
        bf16x8 af[4], bfr[4];
#pragma unroll
        for (int m = 0; m < 4; m++)
            af[m] = *reinterpret_cast<const bf16x8*>(As[cur] + (wm + m * 16 + lr) * 32 + lg * 8);
#pragma unroll
        for (int n = 0; n < 4; n++)
            bfr[n] = *reinterpret_cast<const bf16x8*>(Bs[cur] + (wn + n * 16 + lr) * 32 + lg * 8);
#pragma unroll
        for (int m = 0; m < 4; m++)
#pragma unroll
            for (int n = 0; n < 4; n++)
                acc[m][n] = MFMA_BF16(af[m], bfr[n], acc[m][n]);
        __syncthreads();
    }

#pragma unroll
    for (int m = 0; m < 4; m++) {
#pragma unroll
        for (int n = 0; n < 4; n++) {
            int col = col0 + wn + n * 16 + lr;
#pragma unroll
            for (int i = 0; i < 4; i++) {
                int row = row0 + wm + m * 16 + lg * 4 + i;
                float v = acc[m][n][i];
                if (BIAS) v += bias[col];
                if (GELU) v = 0.5f * v * (1.f + erff(v * 0.70710678118f));
                if (RES)  v += resid[(size_t)row * N + col];
                if (OBF16) ((ushort*)Cout)[(size_t)row * N + col] = f2bf(v);
                else       ((float*)Cout)[(size_t)row * N + col] = v;
            }
        }
    }
}

// ---------------- QKV GEMM (8 waves, 128x256) fused RoPE + V^T (R14 exact) ----------
__global__ __launch_bounds__(512) void gemm_qkv512(const ushort* __restrict__ A,
                                                   const ushort* __restrict__ Bt,
                                                   const float2* __restrict__ tab,
                                                   ushort* __restrict__ Qr,
                                                   ushort* __restrict__ Kr,
                                                   ushort* __restrict__ VT) {
    const int K = DIM_;
    __shared__ __align__(16) ushort As[2][128 * 32];
    __shared__ __align__(16) ushort Bs[2][256 * 32];
    int tid = threadIdx.x;
    int wid = tid >> 6, lane = tid & 63;
    int lr = lane & 15, lg = lane >> 4;

    int nbx = gridDim.x;
    int nwg = nbx * gridDim.y;
    int bid = blockIdx.y * nbx + blockIdx.x;
    int swz = (bid & 7) * (nwg >> 3) + (bid >> 3);
    int row0 = (swz / nbx) * 128, col0 = (swz % nbx) * 256;

    int wm = (wid >> 2) * 64, wn = (wid & 3) * 64;
    int srow = tid >> 2, scol = (tid & 3) * 8;

    f32x4 acc[4][4] = {};

    const ushort* gA = A + (size_t)(row0 + srow) * K + scol;
    const ushort* gB = Bt + (size_t)(col0 + srow) * K + scol;

    auto stage = [&](int buf, int kt) {
        GLOAD_LDS16(gA + kt, As[buf] + wid * 512);
        GLOAD_LDS16(gB + kt, Bs[buf] + wid * 512);
        GLOAD_LDS16(gB + (size_t)128 * K + kt, Bs[buf] + 4096 + wid * 512);
    };

    int nk = K >> 5;
    stage(0, 0);
    __syncthreads();

    for (int t = 0; t < nk; t++) {
        int cur = t & 1;
        if (t + 1 < nk) stage(cur ^ 1, (t + 1) << 5);
        bf16x8 af[4], bfr[4];
#pragma unroll
        for (int m = 0; m < 4; m++)
            af[m] = *reinterpret_cast<const bf16x8*>(As[cur] + (wm + m * 16 + lr) * 32 + lg * 8);
#pragma unroll
        for (int n = 0; n < 4; n++)
            bfr[n] = *reinterpret_cast<const bf16x8*>(Bs[cur] + (wn + n * 16 + lr) * 32 + lg * 8);
#pragma unroll
        for (int m = 0; m < 4; m++)
#pragma unroll
            for (int n = 0; n < 4; n++)
                acc[m][n] = MFMA_BF16(af[m], bfr[n], acc[m][n]);
        __syncthreads();
    }

#pragma unroll
    for (int n = 0; n < 4; n++) {
        int colb = col0 + wn + n * 16;     // uniform per fragment; 16-aligned in a 64-block
        int h    = colb / 192;
        int off  = colb % 192;
        int typ  = off >> 6;               // 0=q, 1=k, 2=v
        int d    = (off & 63) + lr;        // per-lane head dim
#pragma unroll
        for (int m = 0; m < 4; m++) {
            if (typ < 2) {
                ushort* qk = (typ == 0) ? Qr : Kr;
#pragma unroll
                for (int i = 0; i < 4; i++) {
                    int row = row0 + wm + m * 16 + lg * 4 + i;
                    int b = row >> 11, s = row & (S_ - 1);
                    float v  = acc[m][n][i];
                    float pv = __shfl_xor(v, 1);   // partner lane holds x_{d^1}
                    float2 cs = tab[(s << 5) + (d >> 1)];
                    float r = v * cs.x + ((d & 1) ? pv : -pv) * cs.y;
                    qk[((size_t)(b * H_ + h) * S_ + s) * DH_ + d] = f2bf(r);
                }
            } else {
                int row = row0 + wm + m * 16 + lg * 4;
                int b = row >> 11, s = row & (S_ - 1);
                ushort4 o4;
                o4.x = f2bf(acc[m][n][0]);
                o4.y = f2bf(acc[m][n][1]);
                o4.z = f2bf(acc[m][n][2]);
                o4.w = f2bf(acc[m][n][3]);
                *reinterpret_cast<ushort4*>(
                    VT + ((size_t)(b * H_ + h) * DH_ + d) * S_ + s) = o4;
            }
        }
    }
}

// ---------------- RoPE table ---------------------------------------------------------
__global__ __launch_bounds__(256) void rope_table(float2* __restrict__ tab) {
    int i = blockIdx.x * 256 + threadIdx.x;  // S_*32 threads
    int s = i >> 5, p = i & 31;
    float invf = __expf(-((float)(2 * p) / 64.f) * logf(10000.f));
    float a = (float)s * invf;
    tab[i] = make_float2(cosf(a), sinf(a));
}

// ---------------- Flash attention (exact R9/R6 structure, measured 126-128 us) ------
__global__ __launch_bounds__(256) void attn_kernel(const ushort* __restrict__ Q,
                                                   const ushort* __restrict__ Kr,
                                                   const ushort* __restrict__ VT,
                                                   const float* __restrict__ bias,
                                                   const int* __restrict__ pad,
                                                   ushort* __restrict__ Out) {
    int bx = blockIdx.x;
    int qt = bx & 31, h = (bx >> 5) & 15, b = bx >> 9;
    __shared__ __align__(16) ushort Ks[64 * 72];
    __shared__ __align__(16) ushort Vs[64 * 72];
    __shared__ __align__(16) ushort Ps[64 * 72];  // 4 waves x 16 rows
    int tid = threadIdx.x, wid = tid >> 6, lane = tid & 63;
    int lr = lane & 15, lg = lane >> 4;
    int q0 = qt * 64;
    const ushort* Qb = Q + ((size_t)(b * H_ + h) * S_) * DH_;
    const ushort* Kb = Kr + ((size_t)(b * H_ + h) * S_) * DH_;
    const ushort* Vb = VT + ((size_t)(b * H_ + h) * DH_) * S_;
    const float*  bb = bias + (size_t)b * S_ * S_;
    const int*    pb = pad + b * S_;

    bf16x8 qf[2];
#pragma unroll
    for (int ks = 0; ks < 2; ks++)
        qf[ks] = *reinterpret_cast<const bf16x8*>(
            Qb + (size_t)(q0 + wid * 16 + lr) * DH_ + ks * 32 + lg * 8);

    float mrow[4], lrow[4];
#pragma unroll
    for (int i = 0; i < 4; i++) { mrow[i] = -3e38f; lrow[i] = 0.f; }
    f32x4 o[4] = {};

    int sr = tid >> 3, sc = (tid & 7) * 8;
    const float scale = 0.125f;  // dh^-0.5

    for (int kv0 = 0; kv0 < S_; kv0 += 64) {
        __syncthreads();
#pragma unroll
        for (int cc = 0; cc < 2; cc++) {
            int r = cc * 32 + sr;
            *reinterpret_cast<bf16x8*>(Ks + r * 72 + sc) =
                *reinterpret_cast<const bf16x8*>(Kb + (size_t)(kv0 + r) * DH_ + sc);
            *reinterpret_cast<bf16x8*>(Vs + r * 72 + sc) =
                *reinterpret_cast<const bf16x8*>(Vb + (size_t)r * S_ + kv0 + sc);
        }
        __syncthreads();

        // S = Q K^T
        f32x4 sa[4] = {};
#pragma unroll
        for (int n = 0; n < 4; n++) {
            bf16x8 k0 = *reinterpret_cast<const bf16x8*>(Ks + (n * 16 + lr) * 72 + lg * 8);
            bf16x8 k1 = *reinterpret_cast<const bf16x8*>(Ks + (n * 16 + lr) * 72 + 32 + lg * 8);
            sa[n] = MFMA_BF16(qf[0], k0, sa[n]);
            sa[n] = MFMA_BF16(qf[1], k1, sa[n]);
        }

        int pm[4];
#pragma unroll
        for (int n = 0; n < 4; n++) pm[n] = pb[kv0 + n * 16 + lr];

        // online softmax, rows = q0 + wid*16 + lg*4 + i
#pragma unroll
        for (int i = 0; i < 4; i++) {
            const float* brow = bb + (size_t)(q0 + wid * 16 + lg * 4 + i) * S_ + kv0;
            float sv[4];
            float rmax = -3e38f;
#pragma unroll
            for (int n = 0; n < 4; n++) {
                float s = sa[n][i] * scale + brow[n * 16 + lr];
                if (pm[n]) s = -1e30f;
                sv[n] = s;
                rmax = fmaxf(rmax, s);
            }
#pragma unroll
            for (int msk = 1; msk < 16; msk <<= 1) rmax = fmaxf(rmax, __shfl_xor(rmax, msk));
            float mnew = fmaxf(mrow[i], rmax);
            float resc = __expf(mrow[i] - mnew);
            mrow[i] = mnew;
            float ls = 0.f;
            int prow = (i << 2) | lg;  // bit-swapped physical row (bank-spread)
#pragma unroll
            for (int n = 0; n < 4; n++) {
                float p = __expf(sv[n] - mnew);
                ls += p;
                Ps[(wid * 16 + prow) * 72 + n * 16 + lr] = f2bf(p);
            }
            lrow[i] = lrow[i] * resc + ls;  // per-lane partial sum (reduced at end)
#pragma unroll
            for (int fn = 0; fn < 4; fn++) o[fn][i] *= resc;
        }

        // P A-frags (wave-private Ps: no barrier needed)
        int plr = ((lr & 3) << 2) | (lr >> 2);  // same bit-swap
        bf16x8 pf0 = *reinterpret_cast<const bf16x8*>(Ps + (wid * 16 + plr) * 72 + lg * 8);
        bf16x8 pf1 = *reinterpret_cast<const bf16x8*>(Ps + (wid * 16 + plr) * 72 + 32 + lg * 8);

        // O += P @ V   (V B-frags from V^T rows)
#pragma unroll
        for (int fn = 0; fn < 4; fn++) {
            bf16x8 v0 = *reinterpret_cast<const bf16x8*>(Vs + (fn * 16 + lr) * 72 + lg * 8);
            bf16x8 v1 = *reinterpret_cast<const bf16x8*>(Vs + (fn * 16 + lr) * 72 + 32 + lg * 8);
            o[fn] = MFMA_BF16(pf0, v0, o[fn]);
            o[fn] = MFMA_BF16(pf1, v1, o[fn]);
        }
    }

    // reduce per-lane partial sums across the 16-lane row group
#pragma unroll
    for (int i = 0; i < 4; i++)
#pragma unroll
        for (int msk = 1; msk < 16; msk <<= 1) lrow[i] += __shfl_xor(lrow[i], msk);

#pragma unroll
    for (int fn = 0; fn < 4; fn++)
#pragma unroll
        for (int i = 0; i < 4; i++) {
            int qrow = q0 + wid * 16 + lg * 4 + i;
            Out[(size_t)(b * S_ + qrow) * DIM_ + h * DH_ + fn * 16 + lr] =
                f2bf(o[fn][i] / lrow[i]);
        }
}

// ------------------------------------ launch ----------------------------------------
extern "C" void kernel_launch(void* const* d_in, const int* in_sizes, int n_in,
                              void* d_out, int out_size, void* d_ws, size_t ws_size,
                              hipStream_t stream) {
    const float* x    = (const float*)d_in[0];
    const float* bias = (const float*)d_in[1];
    const float* ln1g = (const float*)d_in[2];
    const float* ln1b = (const float*)d_in[3];
    const float* Wqkv = (const float*)d_in[4];
    const float* Wo   = (const float*)d_in[5];
    const float* ln2g = (const float*)d_in[6];
    const float* ln2b = (const float*)d_in[7];
    const float* W1   = (const float*)d_in[8];
    const float* b1   = (const float*)d_in[9];
    const float* W2   = (const float*)d_in[10];
    const float* b2   = (const float*)d_in[11];
    const int*   pad  = (const int*)d_in[12];
    float* out = (float*)d_out;

    char* ws = (char*)d_ws;
    size_t off = 0;
    auto alloc = [&](size_t bytes) {
        char* p = ws + off;
        off += (bytes + 255) & ~(size_t)255;
        return (void*)p;
    };
    ushort* x1    = (ushort*)alloc((size_t)4096 * 1024 * 2);
    ushort* Wqkvt = (ushort*)alloc((size_t)3072 * 1024 * 2);
    float2* tab   = (float2*)alloc((size_t)S_ * 32 * 8);
    ushort* Qr    = (ushort*)alloc((size_t)B_ * H_ * S_ * DH_ * 2);
    ushort* Kr2   = (ushort*)alloc((size_t)B_ * H_ * S_ * DH_ * 2);
    ushort* attnO = (ushort*)alloc((size_t)4096 * 1024 * 2);
    ushort* Wot   = (ushort*)alloc((size_t)1024 * 1024 * 2);
    float*  xmid  = (float*)alloc((size_t)4096 * 1024 * 4);
    ushort* x2    = (ushort*)alloc((size_t)4096 * 1024 * 2);
    ushort* W1t   = (ushort*)alloc((size_t)4096 * 1024 * 2);
    ushort* h1    = (ushort*)alloc((size_t)4096 * 4096 * 2);
    ushort* W2t   = (ushort*)alloc((size_t)1024 * 4096 * 2);
    // VT aliases h1: VT is consumed by attn_kernel, h1 first written after attn.
    ushort* VT    = h1;  // [B,H,DH,S] = 8 MB

    dim3 tb(32, 8);
    transpose_all<<<12288, tb, 0, stream>>>(Wqkv, Wqkvt, Wo, Wot, W1, W1t, W2, W2t);

    rope_table<<<(S_ * 32) / 256, 256, 0, stream>>>(tab);

    ln_kernel<<<4096, 256, 0, stream>>>(x, ln1g, ln1b, x1);

    // QKV GEMM (128x256, 8 waves) with fused RoPE + V^T epilogue
    gemm_qkv512<<<dim3(12, 32), 512, 0, stream>>>(x1, Wqkvt, tab, Qr, Kr2, VT);

    attn_kernel<<<B_ * H_ * (S_ / 64), 256, 0, stream>>>(Qr, Kr2, VT, bias, pad, attnO);

    // O-proj: 64x128 tile, 2 K-steps/barrier -> 512 blocks (2/CU)
    gemm_bt<1, 2, false, false, true, false><<<dim3(8, 64), 256, 0, stream>>>(
        attnO, Wot, xmid, nullptr, x, 4096, 1024, 1024);

    ln_kernel<<<4096, 256, 0, stream>>>(xmid, ln2g, ln2b, x2);

    // MLP1: 128x256 tile, 8 waves -> 512 blocks
    gemm_bt512<true, true, false, true><<<dim3(16, 32), 512, 0, stream>>>(
        x2, W1t, h1, b1, nullptr, 4096, 4096, 1024);

    // MLP2: 64x128 tile, 2 K-steps/barrier -> 512 blocks (2/CU)
    gemm_bt<1, 2, true, false, true, false><<<dim3(8, 64), 256, 0, stream>>>(
        h1, W2t, out, b2, xmid, 4096, 1024, 4096);
}

// Round 18
// 301.736 us; speedup vs baseline: 1.1340x; 1.0162x over previous
//
#include <hip/hip_runtime.h>
#include <hip/hip_bf16.h>

#define B_   2
#define S_   2048
#define DIM_ 1024
#define H_   16
#define DH_  64
#define MLP_ 4096

typedef __bf16 bf16x8 __attribute__((ext_vector_type(8)));
typedef float  f32x4  __attribute__((ext_vector_type(4)));

__device__ __forceinline__ ushort f2bf(float f) {
    __bf16 h = (__bf16)f;                    // RNE; compiler packs pairs into v_cvt_pk_bf16_f32
    return __builtin_bit_cast(ushort, h);
}
__device__ __forceinline__ float bf2f(ushort b) {
    union { unsigned u; float f; } x; x.u = ((unsigned)b) << 16;
    return x.f;
}

#define GLOAD_LDS16(gptr, lptr)                                                        \
    __builtin_amdgcn_global_load_lds(                                                  \
        (const __attribute__((address_space(1))) unsigned int*)(const void*)(gptr),    \
        (__attribute__((address_space(3))) unsigned int*)(void*)(lptr), 16, 0, 0)

#define MFMA_BF16(a, b, c) __builtin_amdgcn_mfma_f32_16x16x32_bf16((a), (b), (c), 0, 0, 0)

// ---------------- prep: 4 weight transposes + RoPE table + LN1, one launch ----------
// blocks [0,12288): transposes; [12288,12544): rope table; [12544,16640): LN1 rows.
__global__ __launch_bounds__(256) void prep_all(const float* __restrict__ Wqkv, ushort* __restrict__ Wqkvt,
                                                const float* __restrict__ Wo,   ushort* __restrict__ Wot,
                                                const float* __restrict__ W1,   ushort* __restrict__ W1t,
                                                const float* __restrict__ W2,   ushort* __restrict__ W2t,
                                                float2* __restrict__ tab,
                                                const float* __restrict__ x,
                                                const float* __restrict__ ln1g,
                                                const float* __restrict__ ln1b,
                                                ushort* __restrict__ x1) {
    __shared__ float t[32][33];
    __shared__ float red[8];
    int id = blockIdx.x, tid = threadIdx.x;
    if (id < 12288) {
        const float* in; ushort* outp; int K, N, nx;
        if (id < 3072)      { in = Wqkv; outp = Wqkvt; K = 1024; N = 3072; nx = 96;  }
        else if (id < 4096) { id -= 3072; in = Wo; outp = Wot;  K = 1024; N = 1024; nx = 32;  }
        else if (id < 8192) { id -= 4096; in = W1; outp = W1t;  K = 1024; N = 4096; nx = 128; }
        else                { id -= 8192; in = W2; outp = W2t;  K = 4096; N = 1024; nx = 32;  }
        int n0 = (id % nx) * 32, k0 = (id / nx) * 32;
        int tx = tid & 31, ty = tid >> 5;
#pragma unroll
        for (int r = 0; r < 32; r += 8)
            t[ty + r][tx] = in[(size_t)(k0 + ty + r) * N + n0 + tx];
        __syncthreads();
#pragma unroll
        for (int r = 0; r < 32; r += 8)
            outp[(size_t)(n0 + ty + r) * K + k0 + tx] = f2bf(t[tx][ty + r]);
    } else if (id < 12544) {
        int i = (id - 12288) * 256 + tid;   // S_*32 entries
        int s = i >> 5, p = i & 31;
        float invf = __expf(-((float)(2 * p) / 64.f) * logf(10000.f));
        float a = (float)s * invf;
        tab[i] = make_float2(cosf(a), sinf(a));
    } else {
        int row = id - 12544;
        float4 v = reinterpret_cast<const float4*>(x + (size_t)row * DIM_)[tid];
        float s = v.x + v.y + v.z + v.w;
        float s2 = v.x * v.x + v.y * v.y + v.z * v.z + v.w * v.w;
#pragma unroll
        for (int m = 1; m < 64; m <<= 1) { s += __shfl_xor(s, m); s2 += __shfl_xor(s2, m); }
        int wid = tid >> 6;
        if ((tid & 63) == 0) { red[wid] = s; red[4 + wid] = s2; }
        __syncthreads();
        s  = red[0] + red[1] + red[2] + red[3];
        s2 = red[4] + red[5] + red[6] + red[7];
        float mean = s * (1.f / DIM_);
        float var  = s2 * (1.f / DIM_) - mean * mean;
        float inv  = rsqrtf(var + 1e-5f);
        float4 gg = reinterpret_cast<const float4*>(ln1g)[tid];
        float4 bb = reinterpret_cast<const float4*>(ln1b)[tid];
        ushort4 o;
        o.x = f2bf((v.x - mean) * inv * gg.x + bb.x);
        o.y = f2bf((v.y - mean) * inv * gg.y + bb.y);
        o.z = f2bf((v.z - mean) * inv * gg.z + bb.z);
        o.w = f2bf((v.w - mean) * inv * gg.w + bb.w);
        reinterpret_cast<ushort4*>(x1 + (size_t)row * DIM_)[tid] = o;
    }
}

// ---------------- LayerNorm, bf16 in -> bf16 out, one block per row -----------------
__global__ __launch_bounds__(256) void ln_bf16(const ushort* __restrict__ in,
                                               const float* __restrict__ g,
                                               const float* __restrict__ beta,
                                               ushort* __restrict__ out) {
    int row = blockIdx.x;
    ushort4 u = reinterpret_cast<const ushort4*>(in + (size_t)row * DIM_)[threadIdx.x];
    float vx = bf2f(u.x), vy = bf2f(u.y), vz = bf2f(u.z), vw = bf2f(u.w);
    float s = vx + vy + vz + vw;
    float s2 = vx * vx + vy * vy + vz * vz + vw * vw;
#pragma unroll
    for (int m = 1; m < 64; m <<= 1) { s += __shfl_xor(s, m); s2 += __shfl_xor(s2, m); }
    __shared__ float red[8];
    int wid = threadIdx.x >> 6;
    if ((threadIdx.x & 63) == 0) { red[wid] = s; red[4 + wid] = s2; }
    __syncthreads();
    s  = red[0] + red[1] + red[2] + red[3];
    s2 = red[4] + red[5] + red[6] + red[7];
    float mean = s * (1.f / DIM_);
    float var  = s2 * (1.f / DIM_) - mean * mean;
    float inv  = rsqrtf(var + 1e-5f);
    float4 gg = reinterpret_cast<const float4*>(g)[threadIdx.x];
    float4 bb = reinterpret_cast<const float4*>(beta)[threadIdx.x];
    ushort4 o;
    o.x = f2bf((vx - mean) * inv * gg.x + bb.x);
    o.y = f2bf((vy - mean) * inv * gg.y + bb.y);
    o.z = f2bf((vz - mean) * inv * gg.z + bb.z);
    o.w = f2bf((vw - mean) * inv * gg.w + bb.w);
    reinterpret_cast<ushort4*>(out + (size_t)row * DIM_)[threadIdx.x] = o;
}

// ---------------- GEMM (4 waves): tile (RM*64)x(RN*64), 2 K-steps per barrier -------
// RB: residual buffer is bf16 (else f32).
template <int RM, int RN, bool BIAS, bool GELU, bool RES, bool RB, bool OBF16>
__global__ __launch_bounds__(256) void gemm_bt(const ushort* __restrict__ A,
                                               const ushort* __restrict__ Bt,
                                               void* __restrict__ Cout,
                                               const float* __restrict__ bias,
                                               const void* __restrict__ resid,
                                               int M, int N, int K) {
    constexpr int BM = RM * 64, BN = RN * 64;
    __shared__ __align__(16) ushort As[2][2][BM * 32];
    __shared__ __align__(16) ushort Bs[2][2][BN * 32];
    int tid = threadIdx.x;
    int wid = tid >> 6, lane = tid & 63;
    int lr = lane & 15, lg = lane >> 4;

    int nbx = gridDim.x;
    int nwg = nbx * gridDim.y;
    int bid = blockIdx.y * nbx + blockIdx.x;
    int swz = (bid & 7) * (nwg >> 3) + (bid >> 3);  // bijective: nwg % 8 == 0
    int row0 = (swz / nbx) * BM, col0 = (swz % nbx) * BN;

    int wm = (wid >> 1) * (RM * 32), wn = (wid & 1) * (RN * 32);
    int srow = tid >> 2, scol = (tid & 3) * 8;

    f32x4 acc[RM * 2][RN * 2] = {};

    const ushort* gA = A + (size_t)(row0 + srow) * K + scol;
    const ushort* gB = Bt + (size_t)(col0 + srow) * K + scol;

    auto stage = [&](int buf, int sub, int kt) {
#pragma unroll
        for (int r = 0; r < RM; r++)
            GLOAD_LDS16(gA + (size_t)r * 64 * K + kt, As[buf][sub] + r * 2048 + wid * 512);
#pragma unroll
        for (int r = 0; r < RN; r++)
            GLOAD_LDS16(gB + (size_t)r * 64 * K + kt, Bs[buf][sub] + r * 2048 + wid * 512);
    };

    int nk = K >> 5;                 // even for all our shapes (32 or 128)
    stage(0, 0, 0);
    stage(0, 1, 32);
    __syncthreads();

    for (int t = 0; t < nk; t += 2) {
        int cur = (t >> 1) & 1;
        if (t + 2 < nk) {            // prefetch next pair; flies under 2 K-steps of MFMA
            stage(cur ^ 1, 0, (t + 2) << 5);
            stage(cur ^ 1, 1, (t + 3) << 5);
        }
#pragma unroll
        for (int sub = 0; sub < 2; sub++) {
            bf16x8 af[RM * 2], bfr[RN * 2];
#pragma unroll
            for (int m = 0; m < RM * 2; m++)
                af[m] = *reinterpret_cast<const bf16x8*>(As[cur][sub] + (wm + m * 16 + lr) * 32 + lg * 8);
#pragma unroll
            for (int n = 0; n < RN * 2; n++)
                bfr[n] = *reinterpret_cast<const bf16x8*>(Bs[cur][sub] + (wn + n * 16 + lr) * 32 + lg * 8);
#pragma unroll
            for (int m = 0; m < RM * 2; m++)
#pragma unroll
                for (int n = 0; n < RN * 2; n++)
                    acc[m][n] = MFMA_BF16(af[m], bfr[n], acc[m][n]);
        }
        __syncthreads();             // drains prefetch + all reads of cur done
    }

#pragma unroll
    for (int m = 0; m < RM * 2; m++) {
#pragma unroll
        for (int n = 0; n < RN * 2; n++) {
            int col = col0 + wn + n * 16 + lr;
#pragma unroll
            for (int i = 0; i < 4; i++) {
                int row = row0 + wm + m * 16 + lg * 4 + i;
                float v = acc[m][n][i];
                if (BIAS) v += bias[col];
                if (GELU) v = 0.5f * v * (1.f + erff(v * 0.70710678118f));
                if (RES) {
                    size_t idx = (size_t)row * N + col;
                    v += RB ? bf2f(((const ushort*)resid)[idx]) : ((const float*)resid)[idx];
                }
                if (OBF16) ((ushort*)Cout)[(size_t)row * N + col] = f2bf(v);
                else       ((float*)Cout)[(size_t)row * N + col] = v;
            }
        }
    }
}

// ---------------- GEMM (8 waves, 512 thr): 128x256 tile, BK=32 (R14 exact) ----------
template <bool BIAS, bool GELU, bool RES, bool OBF16>
__global__ __launch_bounds__(512) void gemm_bt512(const ushort* __restrict__ A,
                                                  const ushort* __restrict__ Bt,
                                                  void* __restrict__ Cout,
                                                  const float* __restrict__ bias,
                                                  const float* __restrict__ resid,
                                                  int M, int N, int K) {
    __shared__ __align__(16) ushort As[2][128 * 32];
    __shared__ __align__(16) ushort Bs[2][256 * 32];
    int tid = threadIdx.x;
    int wid = tid >> 6, lane = tid & 63;
    int lr = lane & 15, lg = lane >> 4;

    int nbx = gridDim.x;
    int nwg = nbx * gridDim.y;
    int bid = blockIdx.y * nbx + blockIdx.x;
    int swz = (bid & 7) * (nwg >> 3) + (bid >> 3);
    int row0 = (swz / nbx) * 128, col0 = (swz % nbx) * 256;

    int wm = (wid >> 2) * 64, wn = (wid & 3) * 64;
    int srow = tid >> 2, scol = (tid & 3) * 8;   // 512 threads: 128 rows x 4 chunks

    f32x4 acc[4][4] = {};

    const ushort* gA = A + (size_t)(row0 + srow) * K + scol;
    const ushort* gB = Bt + (size_t)(col0 + srow) * K + scol;

    auto stage = [&](int buf, int kt) {
        GLOAD_LDS16(gA + kt, As[buf] + wid * 512);                          // A rows 0-127
        GLOAD_LDS16(gB + kt, Bs[buf] + wid * 512);                          // B rows 0-127
        GLOAD_LDS16(gB + (size_t)128 * K + kt, Bs[buf] + 4096 + wid * 512); // B rows 128-255
    };

    int nk = K >> 5;
    stage(0, 0);
    __syncthreads();

    for (int t = 0; t < nk; t++) {
        int cur = t & 1;
        if (t + 1 < nk) stage(cur ^ 1, (t + 1) << 5);
        bf16x8 af[4], bfr[4];
#pragma unroll
        for (int m = 0; m < 4; m++)
            af[m] = *reinterpret_cast<const bf16x8*>(As[cur] + (wm + m * 16 + lr) * 32 + lg * 8);
#pragma unroll
        for (int n = 0; n < 4; n++)
            bfr[n] = *reinterpret_cast<const bf16x8*>(Bs[cur] + (wn + n * 16 + lr) * 32 + lg * 8);
#pragma unroll
        for (int m = 0; m < 4; m++)
#pragma unroll
            for (int n = 0; n < 4; n++)
                acc[m][n] = MFMA_BF16(af[m], bfr[n], acc[m][n]);
        __syncthreads();
    }

#pragma unroll
    for (int m = 0; m < 4; m++) {
#pragma unroll
        for (int n = 0; n < 4; n++) {
            int col = col0 + wn + n * 16 + lr;
#pragma unroll
            for (int i = 0; i < 4; i++) {
                int row = row0 + wm + m * 16 + lg * 4 + i;
                float v = acc[m][n][i];
                if (BIAS) v += bias[col];
                if (GELU) v = 0.5f * v * (1.f + erff(v * 0.70710678118f));
                if (RES)  v += resid[(size_t)row * N + col];
                if (OBF16) ((ushort*)Cout)[(size_t)row * N + col] = f2bf(v);
                else       ((float*)Cout)[(size_t)row * N + col] = v;
            }
        }
    }
}

// ---------------- QKV GEMM (8 waves, 128x256) fused RoPE + V^T (R14 exact) ----------
__global__ __launch_bounds__(512) void gemm_qkv512(const ushort* __restrict__ A,
                                                   const ushort* __restrict__ Bt,
                                                   const float2* __restrict__ tab,
                                                   ushort* __restrict__ Qr,
                                                   ushort* __restrict__ Kr,
                                                   ushort* __restrict__ VT) {
    const int K = DIM_;
    __shared__ __align__(16) ushort As[2][128 * 32];
    __shared__ __align__(16) ushort Bs[2][256 * 32];
    int tid = threadIdx.x;
    int wid = tid >> 6, lane = tid & 63;
    int lr = lane & 15, lg = lane >> 4;

    int nbx = gridDim.x;
    int nwg = nbx * gridDim.y;
    int bid = blockIdx.y * nbx + blockIdx.x;
    int swz = (bid & 7) * (nwg >> 3) + (bid >> 3);
    int row0 = (swz / nbx) * 128, col0 = (swz % nbx) * 256;

    int wm = (wid >> 2) * 64, wn = (wid & 3) * 64;
    int srow = tid >> 2, scol = (tid & 3) * 8;

    f32x4 acc[4][4] = {};

    const ushort* gA = A + (size_t)(row0 + srow) * K + scol;
    const ushort* gB = Bt + (size_t)(col0 + srow) * K + scol;

    auto stage = [&](int buf, int kt) {
        GLOAD_LDS16(gA + kt, As[buf] + wid * 512);
        GLOAD_LDS16(gB + kt, Bs[buf] + wid * 512);
        GLOAD_LDS16(gB + (size_t)128 * K + kt, Bs[buf] + 4096 + wid * 512);
    };

    int nk = K >> 5;
    stage(0, 0);
    __syncthreads();

    for (int t = 0; t < nk; t++) {
        int cur = t & 1;
        if (t + 1 < nk) stage(cur ^ 1, (t + 1) << 5);
        bf16x8 af[4], bfr[4];
#pragma unroll
        for (int m = 0; m < 4; m++)
            af[m] = *reinterpret_cast<const bf16x8*>(As[cur] + (wm + m * 16 + lr) * 32 + lg * 8);
#pragma unroll
        for (int n = 0; n < 4; n++)
            bfr[n] = *reinterpret_cast<const bf16x8*>(Bs[cur] + (wn + n * 16 + lr) * 32 + lg * 8);
#pragma unroll
        for (int m = 0; m < 4; m++)
#pragma unroll
            for (int n = 0; n < 4; n++)
                acc[m][n] = MFMA_BF16(af[m], bfr[n], acc[m][n]);
        __syncthreads();
    }

#pragma unroll
    for (int n = 0; n < 4; n++) {
        int colb = col0 + wn + n * 16;     // uniform per fragment; 16-aligned in a 64-block
        int h    = colb / 192;
        int off  = colb % 192;
        int typ  = off >> 6;               // 0=q, 1=k, 2=v
        int d    = (off & 63) + lr;        // per-lane head dim
#pragma unroll
        for (int m = 0; m < 4; m++) {
            if (typ < 2) {
                ushort* qk = (typ == 0) ? Qr : Kr;
#pragma unroll
                for (int i = 0; i < 4; i++) {
                    int row = row0 + wm + m * 16 + lg * 4 + i;
                    int b = row >> 11, s = row & (S_ - 1);
                    float v  = acc[m][n][i];
                    float pv = __shfl_xor(v, 1);   // partner lane holds x_{d^1}
                    float2 cs = tab[(s << 5) + (d >> 1)];
                    float r = v * cs.x + ((d & 1) ? pv : -pv) * cs.y;
                    qk[((size_t)(b * H_ + h) * S_ + s) * DH_ + d] = f2bf(r);
                }
            } else {
                int row = row0 + wm + m * 16 + lg * 4;
                int b = row >> 11, s = row & (S_ - 1);
                ushort4 o4;
                o4.x = f2bf(acc[m][n][0]);
                o4.y = f2bf(acc[m][n][1]);
                o4.z = f2bf(acc[m][n][2]);
                o4.w = f2bf(acc[m][n][3]);
                *reinterpret_cast<ushort4*>(
                    VT + ((size_t)(b * H_ + h) * DH_ + d) * S_ + s) = o4;
            }
        }
    }
}

// ---------------- Flash attention (exact R16/R6 structure, measured 126-128 us) -----
// 4 waves x 16 q-rows, KV-tile 64. K row-major [kv][dh], V^T row-major [dh][kv],
// both padded to 72. Ps wave-private with bit-swapped physical rows (no barrier).
__global__ __launch_bounds__(256) void attn_kernel(const ushort* __restrict__ Q,
                                                   const ushort* __restrict__ Kr,
                                                   const ushort* __restrict__ VT,
                                                   const float* __restrict__ bias,
                                                   const int* __restrict__ pad,
                                                   ushort* __restrict__ Out) {
    int bx = blockIdx.x;
    int qt = bx & 31, h = (bx >> 5) & 15, b = bx >> 9;
    __shared__ __align__(16) ushort Ks[64 * 72];
    __shared__ __align__(16) ushort Vs[64 * 72];
    __shared__ __align__(16) ushort Ps[64 * 72];  // 4 waves x 16 rows
    int tid = threadIdx.x, wid = tid >> 6, lane = tid & 63;
    int lr = lane & 15, lg = lane >> 4;
    int q0 = qt * 64;
    const ushort* Qb = Q + ((size_t)(b * H_ + h) * S_) * DH_;
    const ushort* Kb = Kr + ((size_t)(b * H_ + h) * S_) * DH_;
    const ushort* Vb = VT + ((size_t)(b * H_ + h) * DH_) * S_;
    const float*  bb = bias + (size_t)b * S_ * S_;
    const int*    pb = pad + b * S_;

    bf16x8 qf[2];
#pragma unroll
    for (int ks = 0; ks < 2; ks++)
        qf[ks] = *reinterpret_cast<const bf16x8*>(
            Qb + (size_t)(q0 + wid * 16 + lr) * DH_ + ks * 32 + lg * 8);

    float mrow[4], lrow[4];
#pragma unroll
    for (int i = 0; i < 4; i++) { mrow[i] = -3e38f; lrow[i] = 0.f; }
    f32x4 o[4] = {};

    int sr = tid >> 3, sc = (tid & 7) * 8;
    const float scale = 0.125f;  // dh^-0.5

    for (int kv0 = 0; kv0 < S_; kv0 += 64) {
        __syncthreads();
#pragma unroll
        for (int cc = 0; cc < 2; cc++) {
            int r = cc * 32 + sr;
            *reinterpret_cast<bf16x8*>(Ks + r * 72 + sc) =
                *reinterpret_cast<const bf16x8*>(Kb + (size_t)(kv0 + r) * DH_ + sc);
            *reinterpret_cast<bf16x8*>(Vs + r * 72 + sc) =
                *reinterpret_cast<const bf16x8*>(Vb + (size_t)r * S_ + kv0 + sc);
        }
        __syncthreads();

        // S = Q K^T
        f32x4 sa[4] = {};
#pragma unroll
        for (int n = 0; n < 4; n++) {
            bf16x8 k0 = *reinterpret_cast<const bf16x8*>(Ks + (n * 16 + lr) * 72 + lg * 8);
            bf16x8 k1 = *reinterpret_cast<const bf16x8*>(Ks + (n * 16 + lr) * 72 + 32 + lg * 8);
            sa[n] = MFMA_BF16(qf[0], k0, sa[n]);
            sa[n] = MFMA_BF16(qf[1], k1, sa[n]);
        }

        int pm[4];
#pragma unroll
        for (int n = 0; n < 4; n++) pm[n] = pb[kv0 + n * 16 + lr];

        // online softmax, rows = q0 + wid*16 + lg*4 + i
#pragma unroll
        for (int i = 0; i < 4; i++) {
            const float* brow = bb + (size_t)(q0 + wid * 16 + lg * 4 + i) * S_ + kv0;
            float sv[4];
            float rmax = -3e38f;
#pragma unroll
            for (int n = 0; n < 4; n++) {
                float s = sa[n][i] * scale + brow[n * 16 + lr];
                if (pm[n]) s = -1e30f;
                sv[n] = s;
                rmax = fmaxf(rmax, s);
            }
#pragma unroll
            for (int msk = 1; msk < 16; msk <<= 1) rmax = fmaxf(rmax, __shfl_xor(rmax, msk));
            float mnew = fmaxf(mrow[i], rmax);
            float resc = __expf(mrow[i] - mnew);
            mrow[i] = mnew;
            float ls = 0.f;
            int prow = (i << 2) | lg;  // bit-swapped physical row (bank-spread)
#pragma unroll
            for (int n = 0; n < 4; n++) {
                float p = __expf(sv[n] - mnew);
                ls += p;
                Ps[(wid * 16 + prow) * 72 + n * 16 + lr] = f2bf(p);
            }
            lrow[i] = lrow[i] * resc + ls;  // per-lane partial sum (reduced at end)
#pragma unroll
            for (int fn = 0; fn < 4; fn++) o[fn][i] *= resc;
        }

        // P A-frags (wave-private Ps: no barrier needed)
        int plr = ((lr & 3) << 2) | (lr >> 2);  // same bit-swap
        bf16x8 pf0 = *reinterpret_cast<const bf16x8*>(Ps + (wid * 16 + plr) * 72 + lg * 8);
        bf16x8 pf1 = *reinterpret_cast<const bf16x8*>(Ps + (wid * 16 + plr) * 72 + 32 + lg * 8);

        // O += P @ V   (V B-frags from V^T rows)
#pragma unroll
        for (int fn = 0; fn < 4; fn++) {
            bf16x8 v0 = *reinterpret_cast<const bf16x8*>(Vs + (fn * 16 + lr) * 72 + lg * 8);
            bf16x8 v1 = *reinterpret_cast<const bf16x8*>(Vs + (fn * 16 + lr) * 72 + 32 + lg * 8);
            o[fn] = MFMA_BF16(pf0, v0, o[fn]);
            o[fn] = MFMA_BF16(pf1, v1, o[fn]);
        }
    }

    // reduce per-lane partial sums across the 16-lane row group
#pragma unroll
    for (int i = 0; i < 4; i++)
#pragma unroll
        for (int msk = 1; msk < 16; msk <<= 1) lrow[i] += __shfl_xor(lrow[i], msk);

#pragma unroll
    for (int fn = 0; fn < 4; fn++)
#pragma unroll
        for (int i = 0; i < 4; i++) {
            int qrow = q0 + wid * 16 + lg * 4 + i;
            Out[(size_t)(b * S_ + qrow) * DIM_ + h * DH_ + fn * 16 + lr] =
                f2bf(o[fn][i] / lrow[i]);
        }
}

// ------------------------------------ launch ----------------------------------------
extern "C" void kernel_launch(void* const* d_in, const int* in_sizes, int n_in,
                              void* d_out, int out_size, void* d_ws, size_t ws_size,
                              hipStream_t stream) {
    const float* x    = (const float*)d_in[0];
    const float* bias = (const float*)d_in[1];
    const float* ln1g = (const float*)d_in[2];
    const float* ln1b = (const float*)d_in[3];
    const float* Wqkv = (const float*)d_in[4];
    const float* Wo   = (const float*)d_in[5];
    const float* ln2g = (const float*)d_in[6];
    const float* ln2b = (const float*)d_in[7];
    const float* W1   = (const float*)d_in[8];
    const float* b1   = (const float*)d_in[9];
    const float* W2   = (const float*)d_in[10];
    const float* b2   = (const float*)d_in[11];
    const int*   pad  = (const int*)d_in[12];
    float* out = (float*)d_out;

    char* ws = (char*)d_ws;
    size_t off = 0;
    auto alloc = [&](size_t bytes) {
        char* p = ws + off;
        off += (bytes + 255) & ~(size_t)255;
        return (void*)p;
    };
    ushort* x1    = (ushort*)alloc((size_t)4096 * 1024 * 2);
    ushort* Wqkvt = (ushort*)alloc((size_t)3072 * 1024 * 2);
    float2* tab   = (float2*)alloc((size_t)S_ * 32 * 8);
    ushort* Qr    = (ushort*)alloc((size_t)B_ * H_ * S_ * DH_ * 2);
    ushort* Kr2   = (ushort*)alloc((size_t)B_ * H_ * S_ * DH_ * 2);
    ushort* attnO = (ushort*)alloc((size_t)4096 * 1024 * 2);
    ushort* Wot   = (ushort*)alloc((size_t)1024 * 1024 * 2);
    ushort* xmid  = (ushort*)alloc((size_t)4096 * 1024 * 2);   // bf16
    ushort* x2    = (ushort*)alloc((size_t)4096 * 1024 * 2);
    ushort* W1t   = (ushort*)alloc((size_t)4096 * 1024 * 2);
    ushort* h1    = (ushort*)alloc((size_t)4096 * 4096 * 2);
    ushort* W2t   = (ushort*)alloc((size_t)1024 * 4096 * 2);
    // VT aliases h1: VT is consumed by attn_kernel, h1 first written after attn.
    ushort* VT    = h1;  // [B,H,DH,S] = 8 MB

    // prep: 4 transposes + rope table + LN1, one launch
    prep_all<<<16640, 256, 0, stream>>>(Wqkv, Wqkvt, Wo, Wot, W1, W1t, W2, W2t,
                                        tab, x, ln1g, ln1b, x1);

    // QKV GEMM (128x256, 8 waves) with fused RoPE + V^T epilogue
    gemm_qkv512<<<dim3(12, 32), 512, 0, stream>>>(x1, Wqkvt, tab, Qr, Kr2, VT);

    attn_kernel<<<B_ * H_ * (S_ / 64), 256, 0, stream>>>(Qr, Kr2, VT, bias, pad, attnO);

    // O-proj: 64x128 tile, 2 K-steps/barrier; resid = x (f32), out = xmid (bf16)
    gemm_bt<1, 2, false, false, true, false, true><<<dim3(8, 64), 256, 0, stream>>>(
        attnO, Wot, xmid, nullptr, x, 4096, 1024, 1024);

    ln_bf16<<<4096, 256, 0, stream>>>(xmid, ln2g, ln2b, x2);

    // MLP1: 128x256 tile, 8 waves -> 512 blocks
    gemm_bt512<true, true, false, true><<<dim3(16, 32), 512, 0, stream>>>(
        x2, W1t, h1, b1, nullptr, 4096, 4096, 1024);

    // MLP2: 64x128 tile, 2 K-steps/barrier; resid = xmid (bf16), out = f32
    gemm_bt<1, 2, true, false, true, true, false><<<dim3(8, 64), 256, 0, stream>>>(
        h1, W2t, out, b2, xmid, 4096, 1024, 4096);
}